// Round 6
// baseline (6956.825 us; speedup 1.0000x reference)
//
#include <hip/hip_runtime.h>
#include <stdint.h>

// Problem: D-FPS. points_xyz (16, 131072, 3) fp32 -> indices (16, 4096) int32.
//
// Round 20 = round 19 with the register-residency FORCED via inline-asm
// opacity. r19 post-mortem: dur only -2.7% and VGPR_Count stayed 52 (= r16
// baseline) -> the compiler REMATERIALIZED the hoisted LDS loads back into
// the loop (legal: sxy/szz provably unwritten after staging). The DS-cost
// model was never tested. Fix: asm volatile("" : "+v"(x)) on each hoisted
// coord makes its origin opaque -> cannot remat -> must stay in VGPRs.
// Expected ~85-100 VGPR (<=128 keeps the mandatory 4 waves/SIMD).
// VERIFICATION SIGNAL: VGPR_Count must rise to ~80-100, else void.
// Cross-block protocol BYTE-IDENTICAL to r16 (= r8/r13/r14 skeleton).
//
// DS-pipe arithmetic being removed (m134 rates): 16 waves x (8 ds_read_b64 +
// 8 ds_read_b32) ~= 1500 cy/iter serialized on the one DS pipe; measured
// r16 = 4027 cy/iter = ~1500 DS + ~2500 sync/reduce.
//
// Locked-in lessons (r2-r19):
//  - relaxed-only AGENT atomics; tag in every polled word (r7/r8).
//  - ONE relaxed polling wave per block; poll touches ONE line (r5/r10/r17).
//  - NARROW fan-in: 16 publishers; no co-residency (r15).
//  - hardware barrier beats software tag-spin for intra-block ordering (r13).
//  - DPP (VALU-pipe) reductions, never __shfl chains (r16).
//  - compiler remats LDS loads unless values are made opaque (r19).
//  - FMA-chain distance d = fma(dz,dz, fma(dy,dy, dx*dx)), subs exact-rounded
//    (r2: bit-exact vs reference trajectory).
//  - removals help; rearrangements and added traffic regress (r9-r12, r17).

#define BATCH 16
#define NPTS  131072
#define NSAMP 4096
#define NBLK  16                  // blocks per batch
#define TPB   1024                // 16 waves
#define CHUNK (NPTS / NBLK)       // 8192 points per block
#define PPT   (CHUNK / TPB)       // 8 points per thread
#define NWAVE (TPB / 64)

typedef unsigned long long u64;
typedef unsigned int u32;

// ---- DPP 64-bit lexicographic max-reduce helpers --------------------------
// key = dist_bits(32) | ~gi(32): u64 max == (max dist, then min index).
// update_dpp(old=0,...): lanes with no valid source read 0; all real keys
// are > 0, so 0 is the identity.
#define DPP_ROW_SHR(n)  (0x110 | (n))
#define DPP_BCAST15     0x142
#define DPP_BCAST31     0x143

template <int CTRL>
__device__ __forceinline__ u64 dpp_max_step(u64 key) {
    u32 lo = (u32)key, hi = (u32)(key >> 32);
    u32 olo = (u32)__builtin_amdgcn_update_dpp(0, (int)lo, CTRL, 0xF, 0xF, false);
    u32 ohi = (u32)__builtin_amdgcn_update_dpp(0, (int)hi, CTRL, 0xF, 0xF, false);
    u64 o = ((u64)ohi << 32) | (u64)olo;
    return o > key ? o : key;
}

// Full-wave (64 lane) max; result valid in lane 63.
__device__ __forceinline__ u64 dpp_max64(u64 key) {
    key = dpp_max_step<DPP_ROW_SHR(1)>(key);
    key = dpp_max_step<DPP_ROW_SHR(2)>(key);
    key = dpp_max_step<DPP_ROW_SHR(4)>(key);
    key = dpp_max_step<DPP_ROW_SHR(8)>(key);
    key = dpp_max_step<DPP_BCAST15>(key);
    key = dpp_max_step<DPP_BCAST31>(key);
    return key;
}

// Row (16 lane) max over lanes 0..15 (others must hold 0); valid in lane 15.
__device__ __forceinline__ u64 dpp_max16(u64 key) {
    key = dpp_max_step<DPP_ROW_SHR(1)>(key);
    key = dpp_max_step<DPP_ROW_SHR(2)>(key);
    key = dpp_max_step<DPP_ROW_SHR(4)>(key);
    key = dpp_max_step<DPP_ROW_SHR(8)>(key);
    return key;
}

// Global slot word (8B, one per block per parity):
//   [63:32] dist bits (>=0 -> monotone) | [31:15] idx (17b) | [14:0] iter tag
// Poison 0xAA.. -> tag 0x2AAA; zero-init -> tag 0; live tags are 1..4095.
// Ring-2 by parity; ordering via the value-dependence chain (r8-proven).

__global__ void fps_init_kernel(u64* __restrict__ ws) {
    int i = blockIdx.x * blockDim.x + threadIdx.x;
    if (i < BATCH * 2 * NBLK) ws[i] = 0ull;
}

__global__ __launch_bounds__(TPB, 4) void fps_kernel(
        const float* __restrict__ xyz, int* __restrict__ out,
        u64* __restrict__ gslot) {
    const int blk   = blockIdx.x;
    const int b     = blk & 15;    // batch: a batch's 16 blocks share blk%8
    const int chunk = blk >> 4;    //        -> same XCD (round-robin dispatch)
    const int tid   = threadIdx.x;
    const int w     = tid >> 6;
    const int lane  = tid & 63;

    const float* bxyz = xyz + (size_t)b * NPTS * 3;
    const int base = chunk * CHUNK;

    // ---- LDS: staging (read once into regs; kept as residency ballast) ----
    __shared__ float2 sxy[CHUNK];          // 64 KB
    __shared__ float  szz[CHUNK];          // 32 KB
    __shared__ u64 red[NWAVE];
    __shared__ u32 bc;                     // winning index, barrier-ordered
    for (int i = tid; i < CHUNK; i += TPB) {
        size_t p = (size_t)(base + i) * 3;
        sxy[i] = make_float2(bxyz[p + 0], bxyz[p + 1]);
        szz[i] = bxyz[p + 2];
    }
    if (tid == 0 && chunk == 0) out[b * NSAMP] = 0; // iter 0 emits index 0
    __syncthreads();   // staging visibility

    // ---- hoist this thread's 8 loop-invariant points into VGPRs ----
    // Full unroll, compile-time indices only (rule #20), then inline-asm
    // opacity so the compiler CANNOT rematerialize the LDS loads (r19).
    float px[PPT], py[PPT], pz[PPT], pd[PPT];
#pragma unroll
    for (int k = 0; k < PPT; ++k) {
        int i = tid + TPB * k;
        float2 xy = sxy[i];
        px[k] = xy.x;
        py[k] = xy.y;
        pz[k] = szz[i];
        pd[k] = __builtin_inff();
        asm volatile("" : "+v"(px[k]), "+v"(py[k]), "+v"(pz[k]));
    }

    float cx = bxyz[0], cy = bxyz[1], cz = bxyz[2];

    u64* gs = gslot + (size_t)b * 2 * NBLK;   // [2][NBLK]

    for (int it = 1; it < NSAMP; ++it) {
        const int par = it & 1;
        u64* gsp = gs + par * NBLK;

        // ---- update min-dists + local argmax (registers only, no LDS) ----
        // Verified arithmetic (round 2, absmax 0): FMA-contracted
        //   d = fma(dz,dz, fma(dy,dy, dx*dx)), subs exact-rounded.
        float bd = -1.0f;
        int   bk = 0;
#pragma unroll
        for (int k = 0; k < PPT; ++k) {
            float dx = __fsub_rn(px[k], cx);
            float dy = __fsub_rn(py[k], cy);
            float dz = __fsub_rn(pz[k], cz);
            float d  = __builtin_fmaf(dz, dz,
                         __builtin_fmaf(dy, dy, __fmul_rn(dx, dx)));
            float nd = fminf(pd[k], d);
            pd[k] = nd;
            // strict >: earliest k wins (gi ascends with k) = first-occurrence
            if (nd > bd) { bd = nd; bk = k; }
        }
        u32 gi = (u32)(base + tid + TPB * bk);
        u64 key = ((u64)__float_as_uint(bd) << 32) | (u64)(~gi);

        // ---- wave max via DPP (VALU pipe) ----
        key = dpp_max64(key);              // valid in lane 63
        if (lane == 63) red[w] = key;      // plain store; barrier1 orders it
        __syncthreads();                   // barrier1

        if (w == 0) {
            // ---- combine 16 plain keys (real keys > 0; lanes 16+ feed 0) ----
            u64 k2 = (lane < NWAVE) ? red[lane] : 0ull;
            k2 = dpp_max16(k2);            // valid in lane 15
            // ---- ONE relaxed agent store publishes the block winner ----
            if (lane == 15) {
                u32 db  = (u32)(k2 >> 32);
                u32 idx = ~(u32)k2;        // = gi (fits 17 bits)
                __hip_atomic_store(&gsp[chunk],
                                   ((u64)db << 32) | ((u64)idx << 15) | (u64)it,
                                   __ATOMIC_RELAXED, __HIP_MEMORY_SCOPE_AGENT);
            }
            // ---- relaxed poll of the 16 slot words (ONE line; r8 protocol) --
            u64 v; bool ok;
            do {
                v  = (lane < NBLK)
                       ? __hip_atomic_load(&gsp[lane], __ATOMIC_RELAXED,
                                           __HIP_MEMORY_SCOPE_AGENT)
                       : 0ull;
                ok = (lane < NBLK) ? ((v & 0x7FFFull) == (u64)it) : true;
            } while (__ballot(ok) != ~0ull);
            u64 k3 = 0ull;
            if (lane < NBLK) {
                u32 db  = (u32)(v >> 32);
                u32 idx = (u32)((v >> 15) & 0x1FFFFu);
                k3 = ((u64)db << 32) | (u64)(~idx);
            }
            k3 = dpp_max16(k3);            // valid in lane 15
            if (lane == 15) {
                u32 widx = ~(u32)k3;
                if (chunk == 0) out[b * NSAMP + it] = (int)widx;
                bc = widx;                 // plain store; barrier2 orders it
            }
        }
        __syncthreads();                   // barrier2 (orders bc)

        u32 widx = bc;                     // barrier-ordered plain read
        cx = bxyz[3 * (size_t)widx + 0];   // same-address broadcast load
        cy = bxyz[3 * (size_t)widx + 1];
        cz = bxyz[3 * (size_t)widx + 2];
    }
}

extern "C" void kernel_launch(void* const* d_in, const int* in_sizes, int n_in,
                              void* d_out, int out_size, void* d_ws, size_t ws_size,
                              hipStream_t stream) {
    const float* xyz = (const float*)d_in[0];
    int* out = (int*)d_out;
    u64* gslot = (u64*)d_ws;   // [BATCH][2][NBLK] u64 = 4 KB

    hipLaunchKernelGGL(fps_init_kernel, dim3(1), dim3(512), 0, stream, gslot);
    hipLaunchKernelGGL(fps_kernel, dim3(BATCH * NBLK), dim3(TPB), 0, stream,
                       xyz, out, gslot);
}